// Round 9
// baseline (416.729 us; speedup 1.0000x reference)
//
#include <hip/hip_runtime.h>

typedef short s16x8 __attribute__((ext_vector_type(8)));
typedef float f32x4 __attribute__((ext_vector_type(4)));
typedef unsigned short u16;
typedef unsigned int u32;
typedef unsigned long long u64;

#define MFMA16(A,B,C) __builtin_amdgcn_mfma_f32_16x16x32_bf16(A,B,C,0,0,0)

// B=4, S=2048, E=128, H=8, D=64. H*D = 512.

__device__ __forceinline__ u16 f2bf(float f){
  union { float f; u32 u; } v; v.f = f;
  u32 r = v.u + 0x7fffu + ((v.u >> 16) & 1u);   // RNE f32->bf16
  return (u16)(r >> 16);
}

__device__ __forceinline__ s16x8 pack8(float4 a, float4 b){
  s16x8 o;
  o[0]=(short)f2bf(a.x); o[1]=(short)f2bf(a.y); o[2]=(short)f2bf(a.z); o[3]=(short)f2bf(a.w);
  o[4]=(short)f2bf(b.x); o[5]=(short)f2bf(b.y); o[6]=(short)f2bf(b.z); o[7]=(short)f2bf(b.w);
  return o;
}

// ---------------------------------------------------------------- mask dtype
__global__ void detect_mask_kernel(const u32* __restrict__ mask, int* __restrict__ flag){
  u32 v = mask[threadIdx.x];            // 64 threads = 1 wave
  u64 b = __ballot(v <= 1u);
  if (threadIdx.x == 0) *flag = (b == ~0ull) ? 1 : 0;   // 1 => int32 layout
}

// Pack mask into bits: word w covers 64 consecutive k for row (b,q).
__global__ __launch_bounds__(256) void pack_mask_kernel(const void* __restrict__ mask,
                                                        u64* __restrict__ bits,
                                                        const int* __restrict__ flag){
  int w = blockIdx.x * 256 + threadIdx.x;   // 262144 words total
  u64 out = 0;
  if (*flag) {
    const int4* p = (const int4*)mask + (size_t)w * 16;
    #pragma unroll
    for (int i = 0; i < 16; i++){
      int4 v = p[i];
      out |= (u64)(v.x != 0) << (i*4+0);
      out |= (u64)(v.y != 0) << (i*4+1);
      out |= (u64)(v.z != 0) << (i*4+2);
      out |= (u64)(v.w != 0) << (i*4+3);
    }
  } else {
    const uint4* p = (const uint4*)mask + (size_t)w * 4;   // 64 bytes
    #pragma unroll
    for (int i = 0; i < 4; i++){
      uint4 v = p[i];
      u32 ws_[4] = {v.x, v.y, v.z, v.w};
      #pragma unroll
      for (int j = 0; j < 4; j++){
        #pragma unroll
        for (int e = 0; e < 4; e++)
          out |= (u64)((ws_[j] >> (8*e)) & 1u) << (i*16 + j*4 + e);
      }
    }
  }
  bits[w] = out;
}

// ---------------------------------------------------------------- W -> bf16
// 64 blocks: [0,32) pack WQ (512x128 f32), [32,64) pack Wfc. 2048 elems/block.
__global__ __launch_bounds__(256) void pack_w_kernel(const float* __restrict__ WQ,
                                                     const float* __restrict__ Wfc,
                                                     u16* __restrict__ WQb,
                                                     u16* __restrict__ Wfcb){
  int bid = blockIdx.x;
  const float* src = (bid < 32) ? WQ  : Wfc;
  u16*        dst = (bid < 32) ? WQb : Wfcb;
  size_t off = (size_t)(bid & 31)*2048 + (size_t)threadIdx.x*8;
  float4 a = *(const float4*)(src+off);
  float4 b = *(const float4*)(src+off+4);
  *(s16x8*)(dst+off) = pack8(a,b);
}

// ---------------------------------------------------------------- projection
// ROUND-6 kernel with ONE change: B-frags load bf16 W directly (no pack8).
// P[8192][512] (bf16) = X[8192][128] @ W[512][128]^T.
__global__ __launch_bounds__(256) void qkv_proj_kernel(const float* __restrict__ X,
                                                       const u16* __restrict__ Wb,
                                                       u16* __restrict__ P){
  int mt  = blockIdx.x >> 3;          // 64 M-tiles of 128
  int nt2 = blockIdx.x & 7;           // 8 N-tiles of 64
  int tid = threadIdx.x, wv = tid >> 6, lane = tid & 63, g = lane >> 4, c = lane & 15;
  int m0 = mt * 128 + wv * 32;
  int n0 = nt2 * 64;

  f32x4 acc[2][4];
  #pragma unroll
  for (int i = 0; i < 2; i++)
    #pragma unroll
    for (int j = 0; j < 4; j++){ f32x4 z = {0.f,0.f,0.f,0.f}; acc[i][j] = z; }

  #pragma unroll
  for (int ks = 0; ks < 4; ks++){
    int kk = ks * 32 + g * 8;
    s16x8 a[2], bb[4];
    #pragma unroll
    for (int mi = 0; mi < 2; mi++){
      const float* ap = X + (size_t)(m0 + mi*16 + c) * 128 + kk;
      a[mi] = pack8(*(const float4*)ap, *(const float4*)(ap + 4));
    }
    #pragma unroll
    for (int ni = 0; ni < 4; ni++)
      bb[ni] = *(const s16x8*)&Wb[(size_t)(n0 + ni*16 + c) * 128 + kk];
    #pragma unroll
    for (int mi = 0; mi < 2; mi++)
      #pragma unroll
      for (int ni = 0; ni < 4; ni++)
        acc[mi][ni] = MFMA16(a[mi], bb[ni], acc[mi][ni]);
  }
  #pragma unroll
  for (int mi = 0; mi < 2; mi++)
    #pragma unroll
    for (int ni = 0; ni < 4; ni++)
      #pragma unroll
      for (int r = 0; r < 4; r++){
        int row = m0 + mi*16 + g*4 + r;
        int col = n0 + ni*16 + c;
        P[(size_t)row * 512 + col] = f2bf(acc[mi][ni][r]);
      }
}

// ---------------------------------------------------------------- V^T
__global__ __launch_bounds__(256) void transpose_v_kernel(const u16* __restrict__ Pv,
                                                          u16* __restrict__ VT){
  int bh = blockIdx.x >> 6;       // 32
  int ch = blockIdx.x & 63;       // 64 chunks of 32 kpos
  int lane = threadIdx.x & 63, wv = threadIdx.x >> 6;
  const u16* V = Pv + (size_t)bh * 131072;
  u16* T = VT + (size_t)bh * 131072;
  int kbase = ch * 32 + wv * 8;
  s16x8 o;
  #pragma unroll
  for (int j = 0; j < 8; j++)
    o[j] = (short)V[(size_t)(kbase + j) * 64 + lane];
  *(s16x8*)&T[(size_t)lane * 2048 + kbase] = o;
}

// ---------------------------------------------------------------- attention
// Round-6-passing kernel with the qt2 dimension removed: 16 q/wave,
// 1024 blocks = bh(32) x qtile(32), 4 waves, register-prefetched K/V/mask,
// ZERO barriers, wave-private XOR-swizzled P-LDS roundtrip.
__global__ __launch_bounds__(256, 4) void attn_kernel(const u16* __restrict__ Pq,
                                                      const u16* __restrict__ Pk,
                                                      const u16* __restrict__ VT,
                                                      const u64* __restrict__ mbits,
                                                      u16* __restrict__ Z){
  __shared__ u16 plds[4][1024];     // per-wave P [16 q][64 k], XOR-swizzled
  int bid0 = blockIdx.x;
  int bid = (bid0 & 7)*128 + (bid0 >> 3);  // XCD swizzle (1024 = 8*128, bijective)
  int bh = bid >> 5, qt = bid & 31;
  int b = bh >> 3;
  int tid = threadIdx.x, wv = tid >> 6, lane = tid & 63, g = lane >> 4, c = lane & 15;
  const u16* Qh = Pq + (size_t)bh*131072;
  const u16* Kh = Pk + (size_t)bh*131072;
  const u16* Th = VT + (size_t)bh*131072;
  int q0w = qt*64 + wv*16;

  // Q A-frags: row q0w+c, elements d = h*32 + g*8 + j
  s16x8 aq[2];
  #pragma unroll
  for (int h=0; h<2; h++)
    aq[h] = *(const s16x8*)&Qh[(size_t)(q0w+c)*64 + h*32 + g*8];

  const u64* mb = mbits + (size_t)(b*2048 + q0w)*32;

  // tile-0 K/V B-frags + mask (prefetch registers)
  s16x8 kb[4][2], vb[4][2];
  u64 mw[4];
  #pragma unroll
  for (int nt=0; nt<4; nt++)
    #pragma unroll
    for (int h=0; h<2; h++)
      kb[nt][h] = *(const s16x8*)&Kh[(size_t)(nt*16+c)*64 + h*32 + g*8];
  #pragma unroll
  for (int dt=0; dt<4; dt++)
    #pragma unroll
    for (int h=0; h<2; h++)
      vb[dt][h] = *(const s16x8*)&Th[(size_t)(dt*16+c)*2048 + h*32 + g*8];
  #pragma unroll
  for (int r=0; r<4; r++)
    mw[r] = mb[(g*4+r)*32];

  f32x4 zac[4];
  #pragma unroll
  for (int j=0;j<4;j++){ f32x4 z = {0.f,0.f,0.f,0.f}; zac[j]=z; }
  float den[4] = {0.f,0.f,0.f,0.f};
  u16* pw = &plds[wv][0];
  int xc = (c&7)<<3;

  for (int t = 0; t < 32; t++){
    int tn = (t+1)&31;           // clamped: last iter prefetches tile 0 (unused)
    int kvn = tn*64;

    // ---- S = Q K^T (16q x 64k), consumes kb
    f32x4 s[4];
    #pragma unroll
    for (int nt=0; nt<4; nt++){
      f32x4 sa = {0.f,0.f,0.f,0.f};
      sa = MFMA16(aq[0], kb[nt][0], sa);
      sa = MFMA16(aq[1], kb[nt][1], sa);
      s[nt] = sa;
    }
    // ---- prefetch next K (kb now dead; loads hide under exp/LDS phase)
    #pragma unroll
    for (int nt=0; nt<4; nt++)
      #pragma unroll
      for (int h=0; h<2; h++)
        kb[nt][h] = *(const s16x8*)&Kh[(size_t)(kvn+nt*16+c)*64 + h*32 + g*8];

    // ---- mask + exp + den; write P to swizzled wave-private LDS
    #pragma unroll
    for (int r=0; r<4; r++){
      int ql = g*4 + r;
      int xr = (ql&7) << 3;
      #pragma unroll
      for (int nt=0; nt<4; nt++){
        int kpos = nt*16 + c;
        float p = ((mw[r] >> kpos) & 1ull) ? 1.0f : __expf(s[nt][r]);
        den[r] += p;
        pw[ql*64 + (kpos ^ xr)] = f2bf(p);
      }
    }
    // ---- prefetch next mask (mw dead)
    #pragma unroll
    for (int r=0; r<4; r++)
      mw[r] = mb[(g*4+r)*32 + tn];

    // ---- Z += P @ V (A from LDS, same-wave in-order DS), consumes vb
    {
      s16x8 ap0 = *(const s16x8*)&pw[c*64 + ((g*8) ^ xc)];
      s16x8 ap1 = *(const s16x8*)&pw[c*64 + ((32+g*8) ^ xc)];
      #pragma unroll
      for (int dt=0; dt<4; dt++){
        zac[dt] = MFMA16(ap0, vb[dt][0], zac[dt]);
        zac[dt] = MFMA16(ap1, vb[dt][1], zac[dt]);
      }
    }
    // ---- prefetch next V (vb dead; ~1 iteration of latency cover)
    #pragma unroll
    for (int dt=0; dt<4; dt++)
      #pragma unroll
      for (int h=0; h<2; h++)
        vb[dt][h] = *(const s16x8*)&Th[(size_t)(dt*16+c)*2048 + kvn + h*32 + g*8];
  }

  // den: reduce across the 16 col-lanes of each group
  #pragma unroll
  for (int r=0; r<4; r++){
    float d = den[r];
    d += __shfl_xor(d, 1, 64);
    d += __shfl_xor(d, 2, 64);
    d += __shfl_xor(d, 4, 64);
    d += __shfl_xor(d, 8, 64);
    den[r] = 1.0f / d;
  }
  u16* Zh = Z + (size_t)bh*131072;
  #pragma unroll
  for (int dt=0; dt<4; dt++)
    #pragma unroll
    for (int r=0; r<4; r++)
      Zh[(size_t)(q0w + g*4 + r)*64 + dt*16 + c] = f2bf(zac[dt][r] * den[r]);
}

// ---------------------------------------------------------------- fc + LN
// ROUND-6 kernel with ONE change: B-frags load bf16 Wfc directly (no pack8).
// out[row][:] = LayerNorm( inputQ[row][:] + ZR[row][:] @ Wfc^T ).
__global__ __launch_bounds__(256) void fc_ln_kernel(const u16* __restrict__ ZR,
                                                    const u16* __restrict__ Wfcb,
                                                    const float* __restrict__ Xq,
                                                    float* __restrict__ out){
  int tid = threadIdx.x, wv = tid >> 6, lane = tid & 63, g = lane >> 4, c = lane & 15;
  int m0 = blockIdx.x * 64 + wv * 16;

  f32x4 acc[8];
  #pragma unroll
  for (int i = 0; i < 8; i++){ f32x4 z = {0.f,0.f,0.f,0.f}; acc[i] = z; }

  for (int ks = 0; ks < 16; ks++){
    int kk = ks * 32 + g * 8;
    s16x8 a = *(const s16x8*)&ZR[(size_t)(m0 + c) * 512 + kk];
    #pragma unroll
    for (int nt = 0; nt < 8; nt++){
      s16x8 bb = *(const s16x8*)&Wfcb[(size_t)(nt*16 + c) * 512 + kk];
      acc[nt] = MFMA16(a, bb, acc[nt]);
    }
  }
  float xs[8][4];
  float sum[4] = {0.f,0.f,0.f,0.f}, ssq[4] = {0.f,0.f,0.f,0.f};
  #pragma unroll
  for (int r = 0; r < 4; r++){
    int row = m0 + g*4 + r;
    #pragma unroll
    for (int nt = 0; nt < 8; nt++){
      float x = acc[nt][r] + Xq[(size_t)row * 128 + nt*16 + c];
      xs[nt][r] = x; sum[r] += x; ssq[r] += x * x;
    }
  }
  #pragma unroll
  for (int r = 0; r < 4; r++){
    float s_ = sum[r], q_ = ssq[r];
    #pragma unroll
    for (int off = 1; off < 16; off <<= 1){
      s_ += __shfl_xor(s_, off, 64);
      q_ += __shfl_xor(q_, off, 64);
    }
    sum[r] = s_; ssq[r] = q_;
  }
  #pragma unroll
  for (int r = 0; r < 4; r++){
    int row = m0 + g*4 + r;
    float mean = sum[r] * (1.0f/128.0f);
    float var  = ssq[r] * (1.0f/128.0f) - mean * mean;
    float rstd = rsqrtf(var + 1e-5f);
    #pragma unroll
    for (int nt = 0; nt < 8; nt++)
      out[(size_t)row * 128 + nt*16 + c] = (xs[nt][r] - mean) * rstd;
  }
}

// ---------------------------------------------------------------- launch
extern "C" void kernel_launch(void* const* d_in, const int* in_sizes, int n_in,
                              void* d_out, int out_size, void* d_ws, size_t ws_size,
                              hipStream_t stream) {
  const float* inQ  = (const float*)d_in[0];
  const float* inK  = (const float*)d_in[1];
  const float* inV  = (const float*)d_in[2];
  const float* WQ   = (const float*)d_in[3];
  const float* Wfc  = (const float*)d_in[4];
  const void*  mask = (const void*) d_in[5];
  float* out = (float*)d_out;

  // ROUND-6 workspace layout + W-pack buffers at [3MB, 3.25MB). Zero overlays.
  char* ws = (char*)d_ws;
  int* flag  = (int*)ws;                       // [0, 4)
  u64* mbits = (u64*)(ws + (1u << 20));        // [1MB, 3MB)   262144 u64
  u16* WQb   = (u16*)(ws + (3u << 20));        // 128KB
  u16* Wfcb  = (u16*)(ws + (3u << 20) + (128u << 10));   // 128KB
  u16* Pq    = (u16*)(ws + (4u  << 20));       // [4MB, 12MB)  bf16 [8192][512]
  u16* Pk    = (u16*)(ws + (12u << 20));       // [12MB,20MB)
  u16* Pv    = (u16*)(ws + (20u << 20));       // [20MB,28MB)
  u16* VTb   = (u16*)(ws + (28u << 20));       // [28MB,36MB)  per-bh [64][2048]
  u16* Zb    = (u16*)(ws + (36u << 20));       // [36MB,44MB)  per-bh [2048][64]

  detect_mask_kernel<<<dim3(1), dim3(64), 0, stream>>>((const u32*)mask, flag);
  pack_mask_kernel<<<dim3(1024), dim3(256), 0, stream>>>(mask, mbits, flag);
  pack_w_kernel<<<dim3(64), dim3(256), 0, stream>>>(WQ, Wfc, WQb, Wfcb);
  qkv_proj_kernel<<<dim3(512), dim3(256), 0, stream>>>(inQ, WQb, Pq);
  qkv_proj_kernel<<<dim3(512), dim3(256), 0, stream>>>(inK, WQb, Pk);
  qkv_proj_kernel<<<dim3(512), dim3(256), 0, stream>>>(inV, WQb, Pv);
  transpose_v_kernel<<<dim3(2048), dim3(256), 0, stream>>>(Pv, VTb);
  attn_kernel<<<dim3(1024), dim3(256), 0, stream>>>(Pq, Pk, VTb, mbits, Zb);
  fc_ln_kernel<<<dim3(128), dim3(256), 0, stream>>>(Zb, Wfcb, inQ, out);
}

// Round 10
// 308.444 us; speedup vs baseline: 1.3511x; 1.3511x over previous
//
#include <hip/hip_runtime.h>
#include <hip/hip_bf16.h>

typedef short s16x8 __attribute__((ext_vector_type(8)));
typedef float f32x4 __attribute__((ext_vector_type(4)));
typedef unsigned short u16;
typedef unsigned int u32;
typedef unsigned long long u64;

#define MFMA16(A,B,C) __builtin_amdgcn_mfma_f32_16x16x32_bf16(A,B,C,0,0,0)

// B=4, S=2048, E=128, H=8, D=64. H*D = 512.

__device__ __forceinline__ u16 f2bf(float f){
  union { __hip_bfloat16 h; u16 u; } x;
  x.h = __float2bfloat16(f);          // single v_cvt op, RNE
  return x.u;
}

__device__ __forceinline__ u32 pk2(float lo, float hi){
  union { __hip_bfloat162 h; u32 u; } x;
  x.h = __float22bfloat162_rn(make_float2(lo, hi));   // lo -> low 16 bits
  return x.u;
}

__device__ __forceinline__ s16x8 pack8(float4 a, float4 b){
  union { __hip_bfloat162 h[4]; s16x8 v; } u;
  u.h[0] = __float22bfloat162_rn(make_float2(a.x, a.y));
  u.h[1] = __float22bfloat162_rn(make_float2(a.z, a.w));
  u.h[2] = __float22bfloat162_rn(make_float2(b.x, b.y));
  u.h[3] = __float22bfloat162_rn(make_float2(b.z, b.w));
  return u.v;
}

// ---------------------------------------------------------------- mask dtype
__global__ void detect_mask_kernel(const u32* __restrict__ mask, int* __restrict__ flag){
  u32 v = mask[threadIdx.x];            // 64 threads = 1 wave
  u64 b = __ballot(v <= 1u);
  if (threadIdx.x == 0) *flag = (b == ~0ull) ? 1 : 0;   // 1 => int32 layout
}

// Pack mask into bits: word w covers 64 consecutive k for row (b,q).
__global__ __launch_bounds__(256) void pack_mask_kernel(const void* __restrict__ mask,
                                                        u64* __restrict__ bits,
                                                        const int* __restrict__ flag){
  int w = blockIdx.x * 256 + threadIdx.x;   // 262144 words total
  u64 out = 0;
  if (*flag) {
    const int4* p = (const int4*)mask + (size_t)w * 16;
    #pragma unroll
    for (int i = 0; i < 16; i++){
      int4 v = p[i];
      out |= (u64)(v.x != 0) << (i*4+0);
      out |= (u64)(v.y != 0) << (i*4+1);
      out |= (u64)(v.z != 0) << (i*4+2);
      out |= (u64)(v.w != 0) << (i*4+3);
    }
  } else {
    const uint4* p = (const uint4*)mask + (size_t)w * 4;   // 64 bytes
    #pragma unroll
    for (int i = 0; i < 4; i++){
      uint4 v = p[i];
      u32 ws_[4] = {v.x, v.y, v.z, v.w};
      #pragma unroll
      for (int j = 0; j < 4; j++){
        #pragma unroll
        for (int e = 0; e < 4; e++)
          out |= (u64)((ws_[j] >> (8*e)) & 1u) << (i*16 + j*4 + e);
      }
    }
  }
  bits[w] = out;
}

// ---------------------------------------------------------------- W -> bf16
// 64 blocks: [0,32) pack WQ (512x128 f32), [32,64) pack Wfc. 2048 elems/block.
__global__ __launch_bounds__(256) void pack_w_kernel(const float* __restrict__ WQ,
                                                     const float* __restrict__ Wfc,
                                                     u16* __restrict__ WQb,
                                                     u16* __restrict__ Wfcb){
  int bid = blockIdx.x;
  const float* src = (bid < 32) ? WQ  : Wfc;
  u16*        dst = (bid < 32) ? WQb : Wfcb;
  size_t off = (size_t)(bid & 31)*2048 + (size_t)threadIdx.x*8;
  float4 a = *(const float4*)(src+off);
  float4 b = *(const float4*)(src+off+4);
  *(s16x8*)(dst+off) = pack8(a,b);
}

// ---------------------------------------------------------------- projection
// B-frags load bf16 W directly. P[8192][512] = X[8192][128] @ W[512][128]^T.
__global__ __launch_bounds__(256) void qkv_proj_kernel(const float* __restrict__ X,
                                                       const u16* __restrict__ Wb,
                                                       u16* __restrict__ P){
  int mt  = blockIdx.x >> 3;          // 64 M-tiles of 128
  int nt2 = blockIdx.x & 7;           // 8 N-tiles of 64
  int tid = threadIdx.x, wv = tid >> 6, lane = tid & 63, g = lane >> 4, c = lane & 15;
  int m0 = mt * 128 + wv * 32;
  int n0 = nt2 * 64;

  f32x4 acc[2][4];
  #pragma unroll
  for (int i = 0; i < 2; i++)
    #pragma unroll
    for (int j = 0; j < 4; j++){ f32x4 z = {0.f,0.f,0.f,0.f}; acc[i][j] = z; }

  #pragma unroll
  for (int ks = 0; ks < 4; ks++){
    int kk = ks * 32 + g * 8;
    s16x8 a[2], bb[4];
    #pragma unroll
    for (int mi = 0; mi < 2; mi++){
      const float* ap = X + (size_t)(m0 + mi*16 + c) * 128 + kk;
      a[mi] = pack8(*(const float4*)ap, *(const float4*)(ap + 4));
    }
    #pragma unroll
    for (int ni = 0; ni < 4; ni++)
      bb[ni] = *(const s16x8*)&Wb[(size_t)(n0 + ni*16 + c) * 128 + kk];
    #pragma unroll
    for (int mi = 0; mi < 2; mi++)
      #pragma unroll
      for (int ni = 0; ni < 4; ni++)
        acc[mi][ni] = MFMA16(a[mi], bb[ni], acc[mi][ni]);
  }
  #pragma unroll
  for (int mi = 0; mi < 2; mi++)
    #pragma unroll
    for (int ni = 0; ni < 4; ni++)
      #pragma unroll
      for (int r = 0; r < 4; r++){
        int row = m0 + mi*16 + g*4 + r;
        int col = n0 + ni*16 + c;
        P[(size_t)row * 512 + col] = f2bf(acc[mi][ni][r]);
      }
}

// ---------------------------------------------------------------- V^T (pi-permuted)
// VT'[d][t*64 + kt] = V[t*64 + pi^{-1}(kt)][d], pi^{-1}(kt) = (kt&3)*16 + (kt>>2).
// Matches attn's pi-ordered P-LDS so PV dot products line up (permutation-
// invariant sum). Reads stay coalesced (lane = d), writes 16B contiguous.
__global__ __launch_bounds__(256) void transpose_v_kernel(const u16* __restrict__ Pv,
                                                          u16* __restrict__ VT){
  int bh = blockIdx.x >> 6;       // 32
  int ch = blockIdx.x & 63;       // 64 chunks of 32 kpos
  int lane = threadIdx.x & 63, wv = threadIdx.x >> 6;
  const u16* V = Pv + (size_t)bh * 131072;
  u16* T = VT + (size_t)bh * 131072;
  int kbase = ch * 32 + wv * 8;
  s16x8 o;
  #pragma unroll
  for (int j = 0; j < 8; j++){
    int x = kbase + j;
    int src = (x & ~63) | (((x & 3) << 4) | ((x & 63) >> 2));
    o[j] = (short)V[(size_t)src * 64 + lane];
  }
  *(s16x8*)&T[(size_t)lane * 2048 + kbase] = o;
}

// ---------------------------------------------------------------- attention
// ROUND-6-proven skeleton (32 q/wave, 512 blocks, launch_bounds(256,2),
// register-prefetched K/V/mask, ZERO barriers) with a cheaper softmax->PV
// handoff: lane-local P values (k = c,c+16,c+32,c+48) are adjacent under
// pi(k)=(k&15)*4+(k>>4), so each q-row needs just 2 cvt_pk + 1 ds_write_b64
// instead of 32 scalar cvt+ds_write_b16. PV read side identical to round 6.
__global__ __launch_bounds__(256, 2) void attn_kernel(const u16* __restrict__ Pq,
                                                      const u16* __restrict__ Pk,
                                                      const u16* __restrict__ VT,
                                                      const u64* __restrict__ mbits,
                                                      u16* __restrict__ Z){
  __shared__ u16 plds[4][2048];     // per-wave P [32 q][64 k~], XOR-swizzled
  int bid0 = blockIdx.x;
  int bid = (bid0 & 7)*64 + (bid0 >> 3);   // XCD swizzle (512 = 8*64, bijective)
  int bh = bid >> 4, qt = bid & 15;
  int b = bh >> 3;
  int tid = threadIdx.x, wv = tid >> 6, lane = tid & 63, g = lane >> 4, c = lane & 15;
  const u16* Qh = Pq + (size_t)bh*131072;
  const u16* Kh = Pk + (size_t)bh*131072;
  const u16* Th = VT + (size_t)bh*131072;
  int q0w = qt*128 + wv*32;

  // Q A-frags: row q0w+qt2*16+c, elements d = h*32+g*8+j
  s16x8 aq[2][2];
  #pragma unroll
  for (int qt2=0; qt2<2; qt2++)
    #pragma unroll
    for (int h=0; h<2; h++)
      aq[qt2][h] = *(const s16x8*)&Qh[(size_t)(q0w+qt2*16+c)*64 + h*32 + g*8];

  const u64* mb = mbits + (size_t)(b*2048 + q0w)*32;

  // tile-0 K/V B-frags + mask (prefetch registers)
  s16x8 kb[4][2], vb[4][2];
  u64 mw[2][4];
  #pragma unroll
  for (int nt=0; nt<4; nt++)
    #pragma unroll
    for (int h=0; h<2; h++)
      kb[nt][h] = *(const s16x8*)&Kh[(size_t)(nt*16+c)*64 + h*32 + g*8];
  #pragma unroll
  for (int dt=0; dt<4; dt++)
    #pragma unroll
    for (int h=0; h<2; h++)
      vb[dt][h] = *(const s16x8*)&Th[(size_t)(dt*16+c)*2048 + h*32 + g*8];
  #pragma unroll
  for (int qt2=0; qt2<2; qt2++)
    #pragma unroll
    for (int r=0; r<4; r++)
      mw[qt2][r] = mb[(qt2*16+g*4+r)*32];

  f32x4 zac[2][4];
  #pragma unroll
  for (int i=0;i<2;i++)
    #pragma unroll
    for (int j=0;j<4;j++){ f32x4 z = {0.f,0.f,0.f,0.f}; zac[i][j]=z; }
  float den[2][4] = {{0.f,0.f,0.f,0.f},{0.f,0.f,0.f,0.f}};
  u16* pw = &plds[wv][0];
  int xc = (c&7)<<3;

  for (int t = 0; t < 32; t++){
    int tn = (t+1)&31;           // clamped: last iter prefetches tile 0 (unused)
    int kvn = tn*64;

    // ---- S = Q K^T (32q x 64k), consumes kb
    f32x4 s[2][4];
    #pragma unroll
    for (int qt2=0; qt2<2; qt2++)
      #pragma unroll
      for (int nt=0; nt<4; nt++){
        f32x4 sa = {0.f,0.f,0.f,0.f};
        sa = MFMA16(aq[qt2][0], kb[nt][0], sa);
        sa = MFMA16(aq[qt2][1], kb[nt][1], sa);
        s[qt2][nt] = sa;
      }
    // ---- prefetch next K (kb now dead; loads hide under exp/LDS phase)
    #pragma unroll
    for (int nt=0; nt<4; nt++)
      #pragma unroll
      for (int h=0; h<2; h++)
        kb[nt][h] = *(const s16x8*)&Kh[(size_t)(kvn+nt*16+c)*64 + h*32 + g*8];

    // ---- mask + exp + den; pi-packed P write (2 cvt_pk + 1 b64 per q-row)
    #pragma unroll
    for (int qt2=0; qt2<2; qt2++)
      #pragma unroll
      for (int r=0; r<4; r++){
        int ql = qt2*16 + g*4 + r;
        int xr = (ql&7) << 3;
        u64 m = mw[qt2][r];
        float p0 = ((m >> (c     )) & 1ull) ? 1.0f : __expf(s[qt2][0][r]);
        float p1 = ((m >> (c + 16)) & 1ull) ? 1.0f : __expf(s[qt2][1][r]);
        float p2 = ((m >> (c + 32)) & 1ull) ? 1.0f : __expf(s[qt2][2][r]);
        float p3 = ((m >> (c + 48)) & 1ull) ? 1.0f : __expf(s[qt2][3][r]);
        den[qt2][r] += (p0 + p1) + (p2 + p3);
        uint2 w;
        w.x = pk2(p0, p1);
        w.y = pk2(p2, p3);
        *(uint2*)&pw[ql*64 + ((4*c) ^ xr)] = w;   // pi-slots 4c..4c+3, swizzled
      }
    // ---- prefetch next mask (mw dead)
    #pragma unroll
    for (int qt2=0; qt2<2; qt2++)
      #pragma unroll
      for (int r=0; r<4; r++)
        mw[qt2][r] = mb[(qt2*16+g*4+r)*32 + tn];

    // ---- Z += P @ V (A from LDS, same-wave in-order DS), consumes vb
    #pragma unroll
    for (int qt2=0; qt2<2; qt2++){
      int qrow = qt2*16 + c;
      s16x8 ap0 = *(const s16x8*)&pw[qrow*64 + ((g*8) ^ xc)];
      s16x8 ap1 = *(const s16x8*)&pw[qrow*64 + ((32+g*8) ^ xc)];
      #pragma unroll
      for (int dt=0; dt<4; dt++){
        zac[qt2][dt] = MFMA16(ap0, vb[dt][0], zac[qt2][dt]);
        zac[qt2][dt] = MFMA16(ap1, vb[dt][1], zac[qt2][dt]);
      }
    }
    // ---- prefetch next V (vb dead; ~1 iteration of latency cover)
    #pragma unroll
    for (int dt=0; dt<4; dt++)
      #pragma unroll
      for (int h=0; h<2; h++)
        vb[dt][h] = *(const s16x8*)&Th[(size_t)(dt*16+c)*2048 + kvn + h*32 + g*8];
  }

  // den: reduce across the 16 col-lanes of each group
  #pragma unroll
  for (int qt2=0; qt2<2; qt2++)
    #pragma unroll
    for (int r=0; r<4; r++){
      float d = den[qt2][r];
      d += __shfl_xor(d, 1, 64);
      d += __shfl_xor(d, 2, 64);
      d += __shfl_xor(d, 4, 64);
      d += __shfl_xor(d, 8, 64);
      den[qt2][r] = 1.0f / d;
    }
  u16* Zh = Z + (size_t)bh*131072;
  #pragma unroll
  for (int qt2=0; qt2<2; qt2++)
    #pragma unroll
    for (int dt=0; dt<4; dt++)
      #pragma unroll
      for (int r=0; r<4; r++)
        Zh[(size_t)(q0w + qt2*16 + g*4 + r)*64 + dt*16 + c] = f2bf(zac[qt2][dt][r] * den[qt2][r]);
}

// ---------------------------------------------------------------- fc + LN
// Full-K per wave (proven structure), bf16 Wfc direct loads.
// out[row][:] = LayerNorm( inputQ[row][:] + ZR[row][:] @ Wfc^T ).
__global__ __launch_bounds__(256) void fc_ln_kernel(const u16* __restrict__ ZR,
                                                    const u16* __restrict__ Wfcb,
                                                    const float* __restrict__ Xq,
                                                    float* __restrict__ out){
  int tid = threadIdx.x, wv = tid >> 6, lane = tid & 63, g = lane >> 4, c = lane & 15;
  int m0 = blockIdx.x * 64 + wv * 16;

  f32x4 acc[8];
  #pragma unroll
  for (int i = 0; i < 8; i++){ f32x4 z = {0.f,0.f,0.f,0.f}; acc[i] = z; }

  for (int ks = 0; ks < 16; ks++){
    int kk = ks * 32 + g * 8;
    s16x8 a = *(const s16x8*)&ZR[(size_t)(m0 + c) * 512 + kk];
    #pragma unroll
    for (int nt = 0; nt < 8; nt++){
      s16x8 bb = *(const s16x8*)&Wfcb[(size_t)(nt*16 + c) * 512 + kk];
      acc[nt] = MFMA16(a, bb, acc[nt]);
    }
  }
  float xs[8][4];
  float sum[4] = {0.f,0.f,0.f,0.f}, ssq[4] = {0.f,0.f,0.f,0.f};
  #pragma unroll
  for (int r = 0; r < 4; r++){
    int row = m0 + g*4 + r;
    #pragma unroll
    for (int nt = 0; nt < 8; nt++){
      float x = acc[nt][r] + Xq[(size_t)row * 128 + nt*16 + c];
      xs[nt][r] = x; sum[r] += x; ssq[r] += x * x;
    }
  }
  #pragma unroll
  for (int r = 0; r < 4; r++){
    float s_ = sum[r], q_ = ssq[r];
    #pragma unroll
    for (int off = 1; off < 16; off <<= 1){
      s_ += __shfl_xor(s_, off, 64);
      q_ += __shfl_xor(q_, off, 64);
    }
    sum[r] = s_; ssq[r] = q_;
  }
  #pragma unroll
  for (int r = 0; r < 4; r++){
    int row = m0 + g*4 + r;
    float mean = sum[r] * (1.0f/128.0f);
    float var  = ssq[r] * (1.0f/128.0f) - mean * mean;
    float rstd = rsqrtf(var + 1e-5f);
    #pragma unroll
    for (int nt = 0; nt < 8; nt++)
      out[(size_t)row * 128 + nt*16 + c] = (xs[nt][r] - mean) * rstd;
  }
}

// ---------------------------------------------------------------- launch
extern "C" void kernel_launch(void* const* d_in, const int* in_sizes, int n_in,
                              void* d_out, int out_size, void* d_ws, size_t ws_size,
                              hipStream_t stream) {
  const float* inQ  = (const float*)d_in[0];
  const float* inK  = (const float*)d_in[1];
  const float* inV  = (const float*)d_in[2];
  const float* WQ   = (const float*)d_in[3];
  const float* Wfc  = (const float*)d_in[4];
  const void*  mask = (const void*) d_in[5];
  float* out = (float*)d_out;

  char* ws = (char*)d_ws;
  int* flag  = (int*)ws;                       // [0, 4)
  u64* mbits = (u64*)(ws + (1u << 20));        // [1MB, 3MB)   262144 u64
  u16* WQb   = (u16*)(ws + (3u << 20));        // 128KB
  u16* Wfcb  = (u16*)(ws + (3u << 20) + (128u << 10));   // 128KB
  u16* Pq    = (u16*)(ws + (4u  << 20));       // [4MB, 12MB)  bf16 [8192][512]
  u16* Pk    = (u16*)(ws + (12u << 20));       // [12MB,20MB)
  u16* Pv    = (u16*)(ws + (20u << 20));       // [20MB,28MB)
  u16* VTb   = (u16*)(ws + (28u << 20));       // [28MB,36MB)  per-bh [64][2048] pi-order
  u16* Zb    = (u16*)(ws + (36u << 20));       // [36MB,44MB)  per-bh [2048][64]

  detect_mask_kernel<<<dim3(1), dim3(64), 0, stream>>>((const u32*)mask, flag);
  pack_mask_kernel<<<dim3(1024), dim3(256), 0, stream>>>(mask, mbits, flag);
  pack_w_kernel<<<dim3(64), dim3(256), 0, stream>>>(WQ, Wfc, WQb, Wfcb);
  qkv_proj_kernel<<<dim3(512), dim3(256), 0, stream>>>(inQ, WQb, Pq);
  qkv_proj_kernel<<<dim3(512), dim3(256), 0, stream>>>(inK, WQb, Pk);
  qkv_proj_kernel<<<dim3(512), dim3(256), 0, stream>>>(inV, WQb, Pv);
  transpose_v_kernel<<<dim3(2048), dim3(256), 0, stream>>>(Pv, VTb);
  attn_kernel<<<dim3(512), dim3(256), 0, stream>>>(Pq, Pk, VTb, mbits, Zb);
  fc_ln_kernel<<<dim3(128), dim3(256), 0, stream>>>(Zb, Wfcb, inQ, out);
}